// Round 1
// baseline (2087.893 us; speedup 1.0000x reference)
//
#include <hip/hip_runtime.h>
#include <cstdint>
#include <cstddef>

// Problem constants (from reference):
//   inputs [4, 8192, 1024] fp32 -> 32768 tokens x D=1024, contiguous 1024-token
//   chunks per (b, e); expert of row-block rb (128 rows) = (rb>>3)&7.
//   w1 [8, 4096, 1024], w2 [8, 1024, 4096]  (torch Linear [out,in] = [N,K] row-major)
//   b1 [8,4096], b2 [8,1024] (zeros in setup, but applied for correctness)

typedef __bf16 bf16;
typedef __attribute__((ext_vector_type(8))) __bf16 bf16x8;
typedef __attribute__((ext_vector_type(4))) __bf16 bf16x4;
typedef __attribute__((ext_vector_type(4))) float floatx4;

// Async global->LDS DMA, 16B per lane. HW semantics: LDS dest =
// readfirstlane(lds_ptr) + lane*16, so granule indices must be
// lane-contiguous (they are: g = i*256 + wave*64 + lane).
__device__ __forceinline__ void async_copy16(void* lds_ptr, const void* g_ptr) {
  __builtin_amdgcn_global_load_lds(
      (const __attribute__((address_space(1))) uint32_t*)g_ptr,
      (__attribute__((address_space(3))) uint32_t*)lds_ptr,
      16, 0, 0);
}

__global__ __launch_bounds__(256) void cvt_f32_to_bf16(
    const float4* __restrict__ src, bf16x4* __restrict__ dst, int n4) {
  int i = blockIdx.x * 256 + threadIdx.x;
  if (i < n4) {
    float4 v = src[i];
    bf16x4 o = {(bf16)v.x, (bf16)v.y, (bf16)v.z, (bf16)v.w};
    dst[i] = o;
  }
}

// Grouped GEMM, A row-major [32768,K], B = per-expert [N,K] row-major (B^T path).
// Out[m][n] = sum_k A[m][k]*B[e][n][k] + bias[e][n], optional exact gelu.
// Tile 128x128, BK=64, 256 threads = 2x2 waves of 64x64 (4x4 16x16x32 MFMA).
// LDS granule layout (16B granules): granule = kc*128 + row  (kc = k/8 within
// BK tile). ds_read_b128: 16 consecutive lanes hit 16 consecutive granules ->
// conflict-free; staging writes are HW-contiguous per instruction.
template <int KDIM, int NDIM, bool GELU, typename OutT>
__global__ __launch_bounds__(256) void gemm_bt_kernel(
    const bf16* __restrict__ A,      // [32768, KDIM] bf16
    const bf16* __restrict__ Bw,     // [8, NDIM, KDIM] bf16
    const float* __restrict__ bias,  // [8, NDIM] fp32
    OutT* __restrict__ Out) {        // [32768, NDIM]
  __shared__ bf16x8 ldsA[1024];  // 16 KB: 128 rows x 8 kc-granules (BK=64)
  __shared__ bf16x8 ldsB[1024];  // 16 KB

  const int m_blk = blockIdx.x;         // 256 row blocks
  const int n_blk = blockIdx.y;         // NDIM/128 col blocks
  const int e = (m_blk >> 3) & 7;       // expert: 8 row-blocks per 1024-token chunk
  const int tid = threadIdx.x;
  const int lane = tid & 63;
  const int wm = (tid >> 6) & 1;        // wave m position (2x2)
  const int wn = tid >> 7;              // wave n position
  const int lo16 = lane & 15;
  const int quad = lane >> 4;

  const bf16* Ab = A + (size_t)m_blk * 128 * KDIM;
  const bf16* Bb = Bw + (size_t)e * NDIM * KDIM + (size_t)n_blk * 128 * KDIM;

  floatx4 acc[4][4];
#pragma unroll
  for (int i = 0; i < 4; ++i)
#pragma unroll
    for (int j = 0; j < 4; ++j) acc[i][j] = (floatx4)(0.0f);

  for (int kt = 0; kt < KDIM / 64; ++kt) {
    const int k0 = kt * 64;
    __syncthreads();  // protect LDS from overwrite while prior reads in flight
#pragma unroll
    for (int i = 0; i < 4; ++i) {
      const int g = i * 256 + tid;       // granule index, lane-contiguous
      const int r = g & 127;             // tile row
      const int kc = g >> 7;             // 8-elem k-chunk within BK
      async_copy16(&ldsA[g], Ab + (size_t)r * KDIM + (k0 + kc * 8));
      async_copy16(&ldsB[g], Bb + (size_t)r * KDIM + (k0 + kc * 8));
    }
    __syncthreads();  // drains vmcnt (compiler-inserted) then barrier
#pragma unroll
    for (int kk = 0; kk < 2; ++kk) {  // two K=32 MFMA steps per BK=64
      bf16x8 af[4], bfv[4];
      const int kc = kk * 4 + quad;
#pragma unroll
      for (int i = 0; i < 4; ++i) {
        af[i] = ldsA[kc * 128 + wm * 64 + i * 16 + lo16];
        bfv[i] = ldsB[kc * 128 + wn * 64 + i * 16 + lo16];
      }
#pragma unroll
      for (int i = 0; i < 4; ++i)
#pragma unroll
        for (int j = 0; j < 4; ++j)
          acc[i][j] = __builtin_amdgcn_mfma_f32_16x16x32_bf16(af[i], bfv[j],
                                                              acc[i][j], 0, 0, 0);
    }
  }

  // Epilogue. C/D layout (verified m89/m91): col = lane&15, row = quad*4 + reg.
  const float* be = bias + e * NDIM;
#pragma unroll
  for (int j = 0; j < 4; ++j) {
    const int col = n_blk * 128 + wn * 64 + j * 16 + lo16;
    const float bv = be[col];
#pragma unroll
    for (int i = 0; i < 4; ++i) {
#pragma unroll
      for (int r = 0; r < 4; ++r) {
        const size_t row = (size_t)m_blk * 128 + wm * 64 + i * 16 + quad * 4 + r;
        float v = acc[i][j][r] + bv;
        if (GELU) v = 0.5f * v * (1.0f + erff(v * 0.70710678118654752f));
        Out[row * (size_t)NDIM + col] = (OutT)v;
      }
    }
  }
}

extern "C" void kernel_launch(void* const* d_in, const int* in_sizes, int n_in,
                              void* d_out, int out_size, void* d_ws, size_t ws_size,
                              hipStream_t stream) {
  const float* x  = (const float*)d_in[0];   // [4,8192,1024]
  const float* w1 = (const float*)d_in[1];   // [8,4096,1024]
  const float* b1 = (const float*)d_in[2];   // [8,4096]
  const float* w2 = (const float*)d_in[3];   // [8,1024,4096]
  const float* b2 = (const float*)d_in[4];   // [8,1024]
  float* out = (float*)d_out;                // [4,8192,1024] fp32
  char* ws = (char*)d_ws;

  // ws layout (total 448 MiB):
  //   xb  bf16 [32768,1024]  @ 0        (64 MiB)
  //   w1b bf16 [8,4096,1024] @ 64 MiB   (64 MiB)
  //   w2b bf16 [8,1024,4096] @ 128 MiB  (64 MiB)
  //   hb  bf16 [32768,4096]  @ 192 MiB  (256 MiB)
  bf16* xb  = (bf16*)(ws + 0);
  bf16* w1b = (bf16*)(ws + 67108864ull);
  bf16* w2b = (bf16*)(ws + 134217728ull);
  bf16* hb  = (bf16*)(ws + 201326592ull);

  // All three fp32 arrays are 33,554,432 elements.
  const int n4 = 33554432 / 4;
  dim3 cgrid(n4 / 256), cblk(256);
  cvt_f32_to_bf16<<<cgrid, cblk, 0, stream>>>((const float4*)x,  (bf16x4*)xb,  n4);
  cvt_f32_to_bf16<<<cgrid, cblk, 0, stream>>>((const float4*)w1, (bf16x4*)w1b, n4);
  cvt_f32_to_bf16<<<cgrid, cblk, 0, stream>>>((const float4*)w2, (bf16x4*)w2b, n4);

  // GEMM1: h = gelu(x @ w1^T + b1), K=1024, N=4096, bf16 out
  gemm_bt_kernel<1024, 4096, true, bf16>
      <<<dim3(256, 32), dim3(256), 0, stream>>>(xb, w1b, b1, hb);
  // GEMM2: y = h @ w2^T + b2, K=4096, N=1024, fp32 out
  gemm_bt_kernel<4096, 1024, false, float>
      <<<dim3(256, 8), dim3(256), 0, stream>>>(hb, w2b, b2, out);
}

// Round 2
// 1970.386 us; speedup vs baseline: 1.0596x; 1.0596x over previous
//
#include <hip/hip_runtime.h>
#include <cstdint>
#include <cstddef>

// Experts MoE FFN: y = gelu(x @ w1^T + b1) @ w2^T + b2, 8 experts.
//   x [32768,1024] fp32 (row-block rb of 128 rows -> expert (rb>>3)&7)
//   w1 [8,4096,1024], w2 [8,1024,4096] (torch [out,in] = [N,K] row-major: B^T GEMM path)
// Pipeline: fp32->bf16 cvt (x,w1,w2) -> GEMM1 (fused bias+exact gelu, bf16 h)
//           -> GEMM2 (fused bias, fp32 out).
// R1 change: n-fastest 1D grid (A staged from HBM once; B re-reads LLC-resident)
//            + non-temporal h/out stores (stop LLC thrash of the input streams).

typedef __bf16 bf16;
typedef __attribute__((ext_vector_type(8))) __bf16 bf16x8;
typedef __attribute__((ext_vector_type(4))) __bf16 bf16x4;
typedef __attribute__((ext_vector_type(4))) float floatx4;

// Async global->LDS DMA, 16B per lane. LDS dest = wave-uniform base + lane*16,
// so granule indices must be lane-contiguous (g = i*256 + tid is).
__device__ __forceinline__ void async_copy16(void* lds_ptr, const void* g_ptr) {
  __builtin_amdgcn_global_load_lds(
      (const __attribute__((address_space(1))) uint32_t*)g_ptr,
      (__attribute__((address_space(3))) uint32_t*)lds_ptr,
      16, 0, 0);
}

__global__ __launch_bounds__(256) void cvt_f32_to_bf16(
    const float4* __restrict__ src, bf16x4* __restrict__ dst, int n4) {
  int i = blockIdx.x * 256 + threadIdx.x;
  if (i < n4) {
    float4 v = src[i];
    bf16x4 o = {(bf16)v.x, (bf16)v.y, (bf16)v.z, (bf16)v.w};
    dst[i] = o;
  }
}

// Grouped GEMM, A row-major [32768,K], B per-expert [N,K] row-major.
// Out[m][n] = sum_k A[m][k]*B[e][n][k] + bias[e][n]; optional exact gelu.
// Tile 128x128, BK=64, 256 threads = 2x2 waves of 64x64 (4x4 16x16x32 MFMA).
// LDS granule layout: granule = kc*128 + row (kc = k/8 in BK tile) ->
// conflict-free ds_read_b128 and HW-contiguous global_load_lds staging.
template <int KDIM, int NDIM, bool GELU, typename OutT>
__global__ __launch_bounds__(256) void gemm_bt_kernel(
    const bf16* __restrict__ A,      // [32768, KDIM] bf16
    const bf16* __restrict__ Bw,     // [8, NDIM, KDIM] bf16
    const float* __restrict__ bias,  // [8, NDIM] fp32
    OutT* __restrict__ Out) {        // [32768, NDIM]
  __shared__ bf16x8 ldsA[1024];  // 16 KB
  __shared__ bf16x8 ldsB[1024];  // 16 KB

  // n-fastest block order: consecutive blocks share one A tile (stream A once).
  constexpr int NB = NDIM / 128;
  const int n_blk = blockIdx.x % NB;
  const int m_blk = blockIdx.x / NB;
  const int e = (m_blk >> 3) & 7;       // 8 row-blocks per 1024-token expert chunk
  const int tid = threadIdx.x;
  const int lane = tid & 63;
  const int wm = (tid >> 6) & 1;
  const int wn = tid >> 7;
  const int lo16 = lane & 15;
  const int quad = lane >> 4;

  const bf16* Ab = A + (size_t)m_blk * 128 * KDIM;
  const bf16* Bb = Bw + (size_t)e * NDIM * KDIM + (size_t)n_blk * 128 * KDIM;

  floatx4 acc[4][4];
#pragma unroll
  for (int i = 0; i < 4; ++i)
#pragma unroll
    for (int j = 0; j < 4; ++j) acc[i][j] = (floatx4)(0.0f);

  for (int kt = 0; kt < KDIM / 64; ++kt) {
    const int k0 = kt * 64;
    __syncthreads();
#pragma unroll
    for (int i = 0; i < 4; ++i) {
      const int g = i * 256 + tid;       // lane-contiguous granule index
      const int r = g & 127;             // tile row
      const int kc = g >> 7;             // 8-elem k-chunk within BK
      async_copy16(&ldsA[g], Ab + (size_t)r * KDIM + (k0 + kc * 8));
      async_copy16(&ldsB[g], Bb + (size_t)r * KDIM + (k0 + kc * 8));
    }
    __syncthreads();
#pragma unroll
    for (int kk = 0; kk < 2; ++kk) {
      bf16x8 af[4], bfv[4];
      const int kc = kk * 4 + quad;
#pragma unroll
      for (int i = 0; i < 4; ++i) {
        af[i] = ldsA[kc * 128 + wm * 64 + i * 16 + lo16];
        bfv[i] = ldsB[kc * 128 + wn * 64 + i * 16 + lo16];
      }
#pragma unroll
      for (int i = 0; i < 4; ++i)
#pragma unroll
        for (int j = 0; j < 4; ++j)
          acc[i][j] = __builtin_amdgcn_mfma_f32_16x16x32_bf16(af[i], bfv[j],
                                                              acc[i][j], 0, 0, 0);
    }
  }

  // Epilogue. C/D layout: col = lane&15, row = quad*4 + reg (m89/m91).
  const float* be = bias + e * NDIM;
#pragma unroll
  for (int j = 0; j < 4; ++j) {
    const int col = n_blk * 128 + wn * 64 + j * 16 + lo16;
    const float bv = be[col];
#pragma unroll
    for (int i = 0; i < 4; ++i) {
#pragma unroll
      for (int r = 0; r < 4; ++r) {
        const size_t row = (size_t)m_blk * 128 + wm * 64 + i * 16 + quad * 4 + r;
        float v = acc[i][j][r] + bv;
        if (GELU) v = 0.5f * v * (1.0f + erff(v * 0.70710678118654752f));
        // Non-temporal: h/out are written once, never re-read soon on this
        // XCD -- keep them from evicting the A/B streams out of LLC.
        __builtin_nontemporal_store((OutT)v, &Out[row * (size_t)NDIM + col]);
      }
    }
  }
}

extern "C" void kernel_launch(void* const* d_in, const int* in_sizes, int n_in,
                              void* d_out, int out_size, void* d_ws, size_t ws_size,
                              hipStream_t stream) {
  const float* x  = (const float*)d_in[0];   // [4,8192,1024]
  const float* w1 = (const float*)d_in[1];   // [8,4096,1024]
  const float* b1 = (const float*)d_in[2];   // [8,4096]
  const float* w2 = (const float*)d_in[3];   // [8,1024,4096]
  const float* b2 = (const float*)d_in[4];   // [8,1024]
  float* out = (float*)d_out;                // [4,8192,1024] fp32
  char* ws = (char*)d_ws;

  // ws layout (448 MiB): xb 64MiB | w1b 64MiB | w2b 64MiB | hb 256MiB
  bf16* xb  = (bf16*)(ws + 0);
  bf16* w1b = (bf16*)(ws + 67108864ull);
  bf16* w2b = (bf16*)(ws + 134217728ull);
  bf16* hb  = (bf16*)(ws + 201326592ull);

  const int n4 = 33554432 / 4;
  dim3 cgrid(n4 / 256), cblk(256);
  cvt_f32_to_bf16<<<cgrid, cblk, 0, stream>>>((const float4*)x,  (bf16x4*)xb,  n4);
  cvt_f32_to_bf16<<<cgrid, cblk, 0, stream>>>((const float4*)w1, (bf16x4*)w1b, n4);
  cvt_f32_to_bf16<<<cgrid, cblk, 0, stream>>>((const float4*)w2, (bf16x4*)w2b, n4);

  // GEMM1: h = gelu(x @ w1^T + b1), K=1024, N=4096, bf16 out. 8192 blocks.
  gemm_bt_kernel<1024, 4096, true, bf16>
      <<<dim3(8192), dim3(256), 0, stream>>>(xb, w1b, b1, hb);
  // GEMM2: y = h @ w2^T + b2, K=4096, N=1024, fp32 out. 2048 blocks.
  gemm_bt_kernel<4096, 1024, false, float>
      <<<dim3(2048), dim3(256), 0, stream>>>(hb, w2b, b2, out);
}